// Round 18
// baseline (63.253 us; speedup 1.0000x reference)
//
#include <hip/hip_runtime.h>
#include <hip/hip_bf16.h>

// QLSTM: T=512, B=256, D_IN=128, D_H=128.
// Gates are per-batch SCALARS broadcast over hidden dim => h,c uniform across
// hidden dim. comb@W[0] = x@W[0][:128] + h*sum(W[0][128:]).
// R17 (60.1us): cross-launch pipeline, symmetric 4x128 chunks.
// R18: asymmetric chunks {64,192,192,64} (halve unhidden prologue/epilogue),
//      tc/os carry restored (h-mul off the serial cycle).
// Launch i=0..5:  xz chunk | scan chunk | write chunk | tails
//   0: xz c0     | -        | -          |
//   1: xz c1     | scan c0  | -          |
//   2: xz c2     | scan c1  | wr c0      |
//   3: xz c3     | scan c2  | wr c1      |
//   4: -         | scan c3  | wr c2      |
//   5: -         | -        | wr c3      | tails

constexpr int T = 512;
constexpr int Bsz = 256;
constexpr int R = T * Bsz;          // 131072 rows
constexpr int MEMB = 2016;          // memory-role blocks
constexpr int GRID = 32 + MEMB;     // 2048
constexpr int MAXCH = 192;          // largest chunk (LDS sizing)
constexpr float INV2PI = 0.15915494309189535f;

typedef float f4v __attribute__((ext_vector_type(4)));

// tanh(c), |c|<=2.07 (provable bound): odd deg-9 polynomial (no rcp),
// err ~1e-3 typ, <=5e-3 near endpoint.
__device__ __forceinline__ float tanh9(float c) {
    const float y  = c * c;
    const float y2 = y * y;
    const float lo  = fmaf(y, -0.321470f, 0.999168f);
    const float hi  = fmaf(y, 0.0016407f, -0.0199491f);
    const float mid = fmaf(y, hi, 0.101498f);
    return c * fmaf(y2, mid, lo);
}

template<int CTRL>
__device__ __forceinline__ float dppq(float x) {
    return __builtin_bit_cast(float,
        __builtin_amdgcn_mov_dpp(__builtin_bit_cast(int, x), CTRL, 0xF, 0xF, true));
}

__device__ __forceinline__ float wsum(const float* __restrict__ W, int lane) {
    float s = W[128 + lane] + W[192 + lane];
#pragma unroll
    for (int off = 32; off; off >>= 1) s += __shfl_xor(s, off, 64);
    return s;  // butterfly: all lanes hold the sum
}

__global__ __launch_bounds__(256) void pipe_kernel(
    const int xz_t0, const int xz_len,
    const int sc_t0, const int sc_len,
    const int wr_t0, const int wr_len, const int do_tails,
    const float* __restrict__ x,
    const float* __restrict__ Wf, const float* __restrict__ bf, const float* __restrict__ tf,
    const float* __restrict__ Wi, const float* __restrict__ bi, const float* __restrict__ ti,
    const float* __restrict__ Wu, const float* __restrict__ bu, const float* __restrict__ tu,
    const float* __restrict__ Wo, const float* __restrict__ bo, const float* __restrict__ to_,
    float4* __restrict__ xz, float* __restrict__ hscan,
    float* __restrict__ hstate, float* __restrict__ cstate,
    float4* __restrict__ out4)
{
    const int tid = threadIdx.x;

    if (blockIdx.x < 32) {
        // ================= scan role =================
        if (sc_len == 0) return;
        __shared__ float4 zb4[MAXCH * 8];    // <=24 KB, [t_local][bg]
        const int bb = blockIdx.x * 8;

        // stage the chunk z slice
        for (int j = tid; j < sc_len * 8; j += 256)
            zb4[j] = xz[(size_t)(sc_t0 + (j >> 3)) * Bsz + bb + (j & 7)];

        const int l = tid & 63;
        const float swf = wsum(Wf, l) * INV2PI;
        const float swi = wsum(Wi, l) * INV2PI;
        const float swu = wsum(Wu, l) * INV2PI;
        const float swo = wsum(Wo, l) * INV2PI;

        __syncthreads();
        if (tid >= 32) return;               // lanes 0..31 of wave 0 scan

        const int q = tid & 3;               // gate: 0=f 1=i 2=g(tanh) 3=o
        const int batch = bb + (tid >> 2);

        const float sw = (q == 0) ? swf : (q == 1) ? swi : (q == 2) ? swu : swo;

        // deg-5 odd gate polynomial in v = cos(u):
        //   tanh lane (q==2): tanh(v) (err ~1.5e-3);
        //   sigmoid lanes: 0.5 + 0.5*tanh(v/2) folded (err ~1.1e-4).
        const bool tq = (q == 2);
        const float K0 = tq ? 0.0f       : 0.5f;
        const float K1 = tq ? 0.999318f  : 0.249976f;
        const float K3 = tq ? -0.319476f : -0.0206916f;
        const float K5 = tq ? 0.08315f   : 0.00188244f;

        const float* zl = (const float*)zb4 + tid;   // scalar [t*32 + bg*4 + q]
        float* hp = hscan + (size_t)sc_t0 * Bsz + batch;

        // carried state: c, tc, os with fma(tc, os, z) == h*sw + z.
        // chunk resume: tc = h_prev, os = sw reproduces the product exactly.
        float h, c;
        if (sc_t0 == 0) { h = 0.0f; c = 0.0f; }
        else            { h = hstate[batch]; c = cstate[batch]; }
        float tc = h, os = sw;

// serial cycle: u -> cos -> v2 -> t1 -> p -> gown -> dpp -> i*g -> c-fma ->
// tanh9 -> u(next).  os = o*sw and h = o*tc run parallel to tanh9.
#define HSTEP(Y)                                                   \
    {                                                              \
        const float u  = fmaf(tc, os, (Y));                        \
        const float v  = __builtin_amdgcn_cosf(u);                 \
        const float v2 = v * v;                                    \
        const float t1 = fmaf(v2, K5, K3);                         \
        const float p  = fmaf(v2, t1, K1);                         \
        const float gown = fmaf(v, p, K0);                         \
        const float f  = dppq<0x00>(gown);                         \
        const float i  = dppq<0x55>(gown);                         \
        const float g_ = dppq<0xAA>(gown);                         \
        const float o  = dppq<0xFF>(gown);                         \
        c  = fmaf(f, c, i * g_);                                   \
        tc = tanh9(c);                                             \
        os = o * sw;                                               \
        h  = o * tc;                                               \
        *hp = h;                                                   \
        hp += Bsz;                                                 \
    }

        // group-ahead prefetch: next 8-step z-group read into named regs
        // BEFORE the current group is consumed.
        float p0 = zl[0 * 32], p1 = zl[1 * 32], p2 = zl[2 * 32], p3 = zl[3 * 32];
        float p4 = zl[4 * 32], p5 = zl[5 * 32], p6 = zl[6 * 32], p7 = zl[7 * 32];

        for (int tb = 0; tb + 8 < sc_len; tb += 8) {
            const float* zn = zl + (size_t)(tb + 8) * 32;
            const float n0 = zn[0 * 32];
            const float n1 = zn[1 * 32];
            const float n2 = zn[2 * 32];
            const float n3 = zn[3 * 32];
            const float n4 = zn[4 * 32];
            const float n5 = zn[5 * 32];
            const float n6 = zn[6 * 32];
            const float n7 = zn[7 * 32];
            HSTEP(p0); HSTEP(p1); HSTEP(p2); HSTEP(p3);
            HSTEP(p4); HSTEP(p5); HSTEP(p6); HSTEP(p7);
            p0 = n0; p1 = n1; p2 = n2; p3 = n3;
            p4 = n4; p5 = n5; p6 = n6; p7 = n7;
        }
        HSTEP(p0); HSTEP(p1); HSTEP(p2); HSTEP(p3);
        HSTEP(p4); HSTEP(p5); HSTEP(p6); HSTEP(p7);
#undef HSTEP

        hstate[batch] = h;                   // quad lanes: same value, same addr
        cstate[batch] = c;
        return;
    }

    // ================= memory role =================
    const int mb   = blockIdx.x - 32;        // 0..MEMB-1
    const int wv   = tid >> 6;
    const int lane = tid & 63;
    const int hl   = lane & 31;
    const int half = lane >> 5;

    // ---- xz GEMV for [xz_t0, xz_t0+xz_len)
    if (xz_len > 0) {
        const float4 wfv = ((const float4*)Wf)[hl];
        const float4 wiv = ((const float4*)Wi)[hl];
        const float4 wuv = ((const float4*)Wu)[hl];
        const float4 wov = ((const float4*)Wo)[hl];
        const float cf = bf[0] + tf[0];
        const float ci = bi[0] + ti[0];
        const float cu = bu[0] + tu[0];
        const float co = bo[0] + to_[0];

        const int slab = xz_t0 * Bsz;
        const int npairs = xz_len * Bsz / 2;
        for (int p = mb * 4 + wv; p < npairs; p += MEMB * 4) {
            const int row = slab + 2 * p + half;
            const float4 xv = *(const float4*)(x + (size_t)row * 128 + hl * 4);

            float pf = xv.x * wfv.x + xv.y * wfv.y + xv.z * wfv.z + xv.w * wfv.w;
            float pi = xv.x * wiv.x + xv.y * wiv.y + xv.z * wiv.z + xv.w * wiv.w;
            float pu = xv.x * wuv.x + xv.y * wuv.y + xv.z * wuv.z + xv.w * wuv.w;
            float po = xv.x * wov.x + xv.y * wov.y + xv.z * wov.z + xv.w * wov.w;

#pragma unroll
            for (int off = 16; off; off >>= 1) {
                pf += __shfl_xor(pf, off, 64);
                pi += __shfl_xor(pi, off, 64);
                pu += __shfl_xor(pu, off, 64);
                po += __shfl_xor(po, off, 64);
            }
            if (hl == 0) {
                xz[row] = make_float4((pf + cf) * INV2PI, (pi + ci) * INV2PI,
                                      (pu + cu) * INV2PI, (po + co) * INV2PI);
            }
        }
    }

    // ---- broadcast-write for [wr_t0, wr_t0+wr_len)
    if (wr_len > 0) {
        const int slabr = wr_t0 * Bsz;
        const int total = wr_len * Bsz * 32;
        for (int j = mb * 256 + tid; j < total; j += MEMB * 256) {
            const int row = slabr + (j >> 5);
            const float v = hscan[row];
            const f4v val = {v, v, v, v};
            __builtin_nontemporal_store(val, (f4v*)&out4[(size_t)row * 32 + (j & 31)]);
        }
    }

    // ---- tails (hx, cx) in the final launch
    if (do_tails) {
        for (int j = mb * 256 + tid; j < 2 * Bsz * 32; j += MEMB * 256) {
            const int kind = j >> 13;        // 0 = hx, 1 = cx  (8192 f4 each)
            const int r    = (j >> 5) & 255;
            const int col  = j & 31;
            const float v = kind ? cstate[r] : hscan[(size_t)(T - 1) * Bsz + r];
            const f4v val = {v, v, v, v};
            __builtin_nontemporal_store(
                val, (f4v*)&out4[((size_t)R + (size_t)kind * Bsz + r) * 32 + col]);
        }
    }
}

extern "C" void kernel_launch(void* const* d_in, const int* in_sizes, int n_in,
                              void* d_out, int out_size, void* d_ws, size_t ws_size,
                              hipStream_t stream)
{
    const float* x  = (const float*)d_in[0];
    const float* Wf = (const float*)d_in[1];
    const float* bf = (const float*)d_in[2];
    const float* tf = (const float*)d_in[3];
    const float* Wi = (const float*)d_in[4];
    const float* bi = (const float*)d_in[5];
    const float* ti = (const float*)d_in[6];
    const float* Wu = (const float*)d_in[7];
    const float* bu = (const float*)d_in[8];
    const float* tu = (const float*)d_in[9];
    const float* Wo = (const float*)d_in[10];
    const float* bo = (const float*)d_in[11];
    const float* to_ = (const float*)d_in[12];

    float* ws     = (float*)d_ws;
    float4* xz    = (float4*)ws;          // R float4s (4*R floats)
    float* hscan  = ws + 4 * R;           // R floats
    float* hstate = ws + 5 * R;           // Bsz floats
    float* cstate = ws + 5 * R + Bsz;     // Bsz floats

    // chunk schedule {64,192,192,64}; starts {0,64,256,448}
    static const int c0[4] = {0, 64, 256, 448};
    static const int cl[4] = {64, 192, 192, 64};
    // launch i: xz chunk i (i<4) | scan chunk i-1 | write chunk i-2 | tails@5
    for (int i = 0; i < 6; ++i) {
        const int xi = i,     has_x = (i < 4);
        const int si = i - 1, has_s = (si >= 0 && si < 4);
        const int wi = i - 2, has_w = (wi >= 0 && wi < 4);
        pipe_kernel<<<GRID, 256, 0, stream>>>(
            has_x ? c0[xi] : 0, has_x ? cl[xi] : 0,
            has_s ? c0[si] : 0, has_s ? cl[si] : 0,
            has_w ? c0[wi] : 0, has_w ? cl[wi] : 0,
            (i == 5) ? 1 : 0,
            x, Wf, bf, tf, Wi, bi, ti, Wu, bu, tu, Wo, bo, to_,
            xz, hscan, hstate, cstate, (float4*)d_out);
    }
}